// Round 8
// baseline (1634.192 us; speedup 1.0000x reference)
//
#include <hip/hip_runtime.h>
#include <math.h>

#define HDIM 256

typedef float floatx4 __attribute__((ext_vector_type(4)));
typedef __bf16 bf16x8 __attribute__((ext_vector_type(8)));
typedef unsigned short ushortx4 __attribute__((ext_vector_type(4)));
typedef unsigned short ushortx8 __attribute__((ext_vector_type(8)));

#define AS1C(p) ((const __attribute__((address_space(1))) void*)(p))
#define AS3(p)  ((__attribute__((address_space(3))) void*)(p))

__device__ inline unsigned short bf16_rn(float f) {
  unsigned u = __float_as_uint(f);
  return (unsigned short)((u + 0x7FFFu + ((u >> 16) & 1u)) >> 16);
}

__device__ inline void split_f32(float f, unsigned short& h, unsigned short& l) {
  unsigned short hb = bf16_rn(f);
  float hf = __uint_as_float(((unsigned)hb) << 16);
  h = hb;
  l = bf16_rn(f - hf);
}

// ---------------- weight prep: all 5 weights in ONE launch ----------------

__device__ inline void prep_w_body(const float* __restrict__ W,
                                   unsigned short* __restrict__ SH,
                                   unsigned short* __restrict__ SL, int K, int idx) {
  int total = K * 32;
  int chunksPerCb = total >> 1;
  int cb = (idx >= chunksPerCb) ? 1 : 0;
  int rem = idx - cb * chunksPerCb;
  int kt = rem >> 9;
  int chunk = rem & 511;
  int kc = chunk >> 7;
  int col = chunk & 127;
  const float* src = W + (size_t)(kt * 32 + kc * 8) * HDIM + cb * 128 + col;
#pragma unroll
  for (int e = 0; e < 8; ++e) {
    unsigned short h, l;
    split_f32(src[(size_t)e * HDIM], h, l);
    SH[(size_t)idx * 8 + e] = h;
    SL[(size_t)idx * 8 + e] = l;
  }
}

__global__ __launch_bounds__(256)
void prep_w_all(const float* __restrict__ W1, unsigned short* __restrict__ S1H,
                unsigned short* __restrict__ S1L, int K1,
                const float* __restrict__ Wg1, unsigned short* __restrict__ G1H,
                unsigned short* __restrict__ G1L,
                const float* __restrict__ Wg2, unsigned short* __restrict__ G2H,
                unsigned short* __restrict__ G2L,
                const float* __restrict__ W2, unsigned short* __restrict__ S2H,
                unsigned short* __restrict__ S2L,
                const float* __restrict__ W3, unsigned short* __restrict__ S3H,
                unsigned short* __restrict__ S3L) {
  int gidx = blockIdx.x * 256 + threadIdx.x;
  int t1 = K1 * 32;
  int t256 = HDIM * 32;
  if (gidx < t1) {
    prep_w_body(W1, S1H, S1L, K1, gidx);
    return;
  }
  int r = gidx - t1;
  int which = r / t256;
  int idx = r - which * t256;
  if (which == 0)      prep_w_body(Wg1, G1H, G1L, HDIM, idx);
  else if (which == 1) prep_w_body(Wg2, G2H, G2L, HDIM, idx);
  else if (which == 2) prep_w_body(W2, S2H, S2L, HDIM, idx);
  else if (which == 3) prep_w_body(W3, S3H, S3L, HDIM, idx);
}

// ---------------- CSR build ----------------

__global__ __launch_bounds__(256)
void deg_count_kernel(const int* __restrict__ ei, int* __restrict__ deg, int E) {
  int e = blockIdx.x * 256 + threadIdx.x;
  if (e < E) atomicAdd(&deg[ei[E + e]], 1);
}

__global__ __launch_bounds__(256)
void block_sum_kernel(const int* __restrict__ deg, int* __restrict__ bsum,
                      float* __restrict__ dinv, int n) {
  __shared__ int sm[256];
  int t = threadIdx.x;
  int idx = blockIdx.x * 256 + t;
  int v = (idx < n) ? deg[idx] : 0;
  sm[t] = v;
  if (idx < n) dinv[idx] = 1.0f / sqrtf((float)v + 1.0f);
  __syncthreads();
  for (int off = 128; off > 0; off >>= 1) {
    if (t < off) sm[t] += sm[t + off];
    __syncthreads();
  }
  if (t == 0) bsum[blockIdx.x] = sm[0];
}

__global__ __launch_bounds__(256)
void scan_bsums_kernel(const int* __restrict__ bsum, int* __restrict__ boff,
                       int* __restrict__ rowptr, int nb, int n) {
  __shared__ int sm[256];
  int t = threadIdx.x;
  int v = (t < nb) ? bsum[t] : 0;
  sm[t] = v;
  __syncthreads();
  for (int off = 1; off < 256; off <<= 1) {
    int a = (t >= off) ? sm[t - off] : 0;
    __syncthreads();
    sm[t] += a;
    __syncthreads();
  }
  if (t < nb) boff[t] = sm[t] - v;
  if (t == 255) rowptr[n] = sm[255];
}

__global__ __launch_bounds__(256)
void scan_final_kernel(const int* __restrict__ deg, const int* __restrict__ boff,
                       int* __restrict__ rowptr, int* __restrict__ cursor, int n) {
  __shared__ int sm[256];
  int t = threadIdx.x;
  int idx = blockIdx.x * 256 + t;
  int v = (idx < n) ? deg[idx] : 0;
  sm[t] = v;
  __syncthreads();
  for (int off = 1; off < 256; off <<= 1) {
    int a = (t >= off) ? sm[t - off] : 0;
    __syncthreads();
    sm[t] += a;
    __syncthreads();
  }
  int excl = sm[t] - v + boff[blockIdx.x];
  if (idx < n) { rowptr[idx] = excl; cursor[idx] = excl; }
}

__global__ __launch_bounds__(256)
void fill_csr_kernel(const int* __restrict__ ei, const float* __restrict__ dinv,
                     int* __restrict__ cursor, int* __restrict__ col,
                     float* __restrict__ wsrc, int E) {
  int e = blockIdx.x * 256 + threadIdx.x;
  if (e < E) {
    int s = ei[e];
    int d = ei[E + e];
    int p = atomicAdd(&cursor[d], 1);
    col[p] = s;
    wsrc[p] = dinv[s];
  }
}

// ---------------- GEMM 1: fp32 A, in-kernel split, tile 128x256, 512 threads ----------------
// Single-buffered (dbuf tested r1/r7: compiler drains vmcnt(0) at every barrier,
// so prefetch never survives the barrier; the LDS cost only loses the
// 2-resident-block overlap that actually hides the drain).

template<bool BIAS, bool RELU>
__global__ __launch_bounds__(512, 4)
void mfma_gemm_sA(const float* __restrict__ A,
                  const unsigned short* __restrict__ SWH, const unsigned short* __restrict__ SWL,
                  const float* __restrict__ bias,
                  unsigned short* __restrict__ CH, unsigned short* __restrict__ CL,
                  int M, int K) {
  __shared__ __align__(16) unsigned short AsH[4096];
  __shared__ __align__(16) unsigned short AsL[4096];
  __shared__ __align__(16) unsigned short BsH[8192];
  __shared__ __align__(16) unsigned short BsL[8192];

  const int tid = threadIdx.x;
  const int w = tid >> 6;
  const int l = tid & 63;
  const int l15 = l & 15;
  const int quad = l >> 4;
  const int wm = w & 1;
  const int wn = w >> 1;
  const int bm = blockIdx.x * 128;
  const int ktc = K >> 5;
  const int chunksPerCb = ktc * 512;

  floatx4 acc[4][4];
#pragma unroll
  for (int i = 0; i < 4; ++i)
#pragma unroll
    for (int j = 0; j < 4; ++j) acc[i][j] = (floatx4){0.f, 0.f, 0.f, 0.f};

  const int arow = tid >> 2;
  const int ap = tid & 3;
  const int akc = ap ^ (arow & 3) ^ ((arow >> 2) & 3);
  int agrow = bm + arow;
  if (agrow > M - 1) agrow = M - 1;
  const float* agp = A + (size_t)agrow * K + akc * 8;

  for (int kt = 0; kt < ktc; ++kt) {
    float4 f0 = *(const float4*)(agp + kt * 32);
    float4 f1 = *(const float4*)(agp + kt * 32 + 4);

    __syncthreads();

#pragma unroll
    for (int j = 0; j < 2; ++j) {
      int pos = j * 512 + w * 64 + l;
      int kc = pos >> 8;
      int within = pos & 255;
      int cb = within >> 7;
      int colL = within & 127;
      size_t gi = (size_t)cb * chunksPerCb + (size_t)kt * 512 + kc * 128 + colL;
      __builtin_amdgcn_global_load_lds(AS1C(SWH + gi * 8),
                                       AS3(&BsH[(j * 512 + w * 64) * 8]), 16, 0, 0);
      __builtin_amdgcn_global_load_lds(AS1C(SWL + gi * 8),
                                       AS3(&BsL[(j * 512 + w * 64) * 8]), 16, 0, 0);
    }

    {
      float f[8] = {f0.x, f0.y, f0.z, f0.w, f1.x, f1.y, f1.z, f1.w};
      ushortx8 hh, ll;
#pragma unroll
      for (int e = 0; e < 8; ++e) {
        unsigned short h, lo;
        split_f32(f[e], h, lo);
        hh[e] = h;
        ll[e] = lo;
      }
      *(ushortx8*)&AsH[(size_t)tid * 8] = hh;
      *(ushortx8*)&AsL[(size_t)tid * 8] = ll;
    }

    __syncthreads();

    bf16x8 aH[4], aL[4];
#pragma unroll
    for (int fi = 0; fi < 4; ++fi) {
      int r = wm * 64 + fi * 16 + l15;
      int sw = quad ^ (r & 3) ^ ((r >> 2) & 3);
      aH[fi] = *(const bf16x8*)&AsH[(r * 4 + sw) * 8];
      aL[fi] = *(const bf16x8*)&AsL[(r * 4 + sw) * 8];
    }
#pragma unroll
    for (int fj = 0; fj < 4; ++fj) {
      int colG = wn * 64 + fj * 16 + l15;
      int cidx = quad * 256 + colG;
      bf16x8 bh = *(const bf16x8*)&BsH[cidx * 8];
      bf16x8 bl = *(const bf16x8*)&BsL[cidx * 8];
#pragma unroll
      for (int fi = 0; fi < 4; ++fi) {
        floatx4 t = acc[fi][fj];
        t = __builtin_amdgcn_mfma_f32_16x16x32_bf16(aH[fi], bl, t, 0, 0, 0);
        t = __builtin_amdgcn_mfma_f32_16x16x32_bf16(aL[fi], bh, t, 0, 0, 0);
        t = __builtin_amdgcn_mfma_f32_16x16x32_bf16(aH[fi], bh, t, 0, 0, 0);
        acc[fi][fj] = t;
      }
    }
  }

  float bcol[4];
#pragma unroll
  for (int fj = 0; fj < 4; ++fj)
    bcol[fj] = BIAS ? bias[wn * 64 + fj * 16 + l15] : 0.f;

#pragma unroll
  for (int fi = 0; fi < 4; ++fi) {
    int rb = bm + wm * 64 + fi * 16 + quad * 4;
#pragma unroll
    for (int r = 0; r < 4; ++r) {
      int row = rb + r;
      if (row < M) {
        size_t base = (size_t)row * HDIM + wn * 64 + l15;
#pragma unroll
        for (int fj = 0; fj < 4; ++fj) {
          float v = acc[fi][fj][r] + bcol[fj];
          if (RELU) v = fmaxf(v, 0.f);
          unsigned short h, lo;
          split_f32(v, h, lo);
          CH[base + fj * 16] = h;
          CL[base + fj * 16] = lo;
        }
      }
    }
  }
}

// ---------------- plane GEMM: tile 128x256, 512 threads, single-buffered ----------------
// In-place use (CH==AH, CL==AL) safe: block reads only its own 128-row panel
// and writes it strictly after its last stage-read.

template<bool BIAS, bool RELU, bool SPLIT_OUT>
__global__ __launch_bounds__(512, 4)
void mfma_gemm_p(const unsigned short* __restrict__ AH, const unsigned short* __restrict__ AL,
                 const unsigned short* __restrict__ SWH, const unsigned short* __restrict__ SWL,
                 const float* __restrict__ bias,
                 float* __restrict__ C, unsigned short* __restrict__ CH,
                 unsigned short* __restrict__ CL, int M, int K) {
  __shared__ __align__(16) unsigned short AsH[4096];
  __shared__ __align__(16) unsigned short AsL[4096];
  __shared__ __align__(16) unsigned short BsH[8192];
  __shared__ __align__(16) unsigned short BsL[8192];

  const int tid = threadIdx.x;
  const int w = tid >> 6;
  const int l = tid & 63;
  const int l15 = l & 15;
  const int quad = l >> 4;
  const int wm = w & 1;
  const int wn = w >> 1;
  const int bm = blockIdx.x * 128;
  const int ktc = K >> 5;
  const int chunksPerCb = ktc * 512;

  floatx4 acc[4][4];
#pragma unroll
  for (int i = 0; i < 4; ++i)
#pragma unroll
    for (int j = 0; j < 4; ++j) acc[i][j] = (floatx4){0.f, 0.f, 0.f, 0.f};

  for (int kt = 0; kt < ktc; ++kt) {
    __syncthreads();

    {
      int L = tid;
      int row = L >> 2;
      int p = L & 3;
      int kc = p ^ (row & 3) ^ ((row >> 2) & 3);
      int grow = bm + row;
      if (grow > M - 1) grow = M - 1;
      const unsigned short* gH = AH + (size_t)grow * K + kt * 32 + kc * 8;
      const unsigned short* gL = AL + (size_t)grow * K + kt * 32 + kc * 8;
      __builtin_amdgcn_global_load_lds(AS1C(gH), AS3(&AsH[(w * 64) * 8]), 16, 0, 0);
      __builtin_amdgcn_global_load_lds(AS1C(gL), AS3(&AsL[(w * 64) * 8]), 16, 0, 0);
    }
#pragma unroll
    for (int j = 0; j < 2; ++j) {
      int pos = j * 512 + w * 64 + l;
      int kc = pos >> 8;
      int within = pos & 255;
      int cb = within >> 7;
      int colL = within & 127;
      size_t gi = (size_t)cb * chunksPerCb + (size_t)kt * 512 + kc * 128 + colL;
      __builtin_amdgcn_global_load_lds(AS1C(SWH + gi * 8),
                                       AS3(&BsH[(j * 512 + w * 64) * 8]), 16, 0, 0);
      __builtin_amdgcn_global_load_lds(AS1C(SWL + gi * 8),
                                       AS3(&BsL[(j * 512 + w * 64) * 8]), 16, 0, 0);
    }

    __syncthreads();

    bf16x8 aH[4], aL[4];
#pragma unroll
    for (int fi = 0; fi < 4; ++fi) {
      int r = wm * 64 + fi * 16 + l15;
      int sw = quad ^ (r & 3) ^ ((r >> 2) & 3);
      aH[fi] = *(const bf16x8*)&AsH[(r * 4 + sw) * 8];
      aL[fi] = *(const bf16x8*)&AsL[(r * 4 + sw) * 8];
    }
#pragma unroll
    for (int fj = 0; fj < 4; ++fj) {
      int colG = wn * 64 + fj * 16 + l15;
      int cidx = quad * 256 + colG;
      bf16x8 bh = *(const bf16x8*)&BsH[cidx * 8];
      bf16x8 bl = *(const bf16x8*)&BsL[cidx * 8];
#pragma unroll
      for (int fi = 0; fi < 4; ++fi) {
        floatx4 t = acc[fi][fj];
        t = __builtin_amdgcn_mfma_f32_16x16x32_bf16(aH[fi], bl, t, 0, 0, 0);
        t = __builtin_amdgcn_mfma_f32_16x16x32_bf16(aL[fi], bh, t, 0, 0, 0);
        t = __builtin_amdgcn_mfma_f32_16x16x32_bf16(aH[fi], bh, t, 0, 0, 0);
        acc[fi][fj] = t;
      }
    }
  }

  float bcol[4];
#pragma unroll
  for (int fj = 0; fj < 4; ++fj)
    bcol[fj] = BIAS ? bias[wn * 64 + fj * 16 + l15] : 0.f;

#pragma unroll
  for (int fi = 0; fi < 4; ++fi) {
    int rb = bm + wm * 64 + fi * 16 + quad * 4;
#pragma unroll
    for (int r = 0; r < 4; ++r) {
      int row = rb + r;
      if (row < M) {
        size_t base = (size_t)row * HDIM + wn * 64 + l15;
        if (SPLIT_OUT) {
#pragma unroll
          for (int fj = 0; fj < 4; ++fj) {
            float v = acc[fi][fj][r] + bcol[fj];
            if (RELU) v = fmaxf(v, 0.f);
            unsigned short h, lo;
            split_f32(v, h, lo);
            CH[base + fj * 16] = h;
            CL[base + fj * 16] = lo;
          }
        } else {
#pragma unroll
          for (int fj = 0; fj < 4; ++fj) {
            float v = acc[fi][fj][r] + bcol[fj];
            if (RELU) v = fmaxf(v, 0.f);
            C[base + fj * 16] = v;
          }
        }
      }
    }
  }
}

// ---------------- fused GEMM + softmax: tile 128x256, 512 threads ----------------
// Reads A-planes from workspace, writes fp32 to d_out: disjoint regions.

__global__ __launch_bounds__(512, 4)
void mfma_gemm_softmax(const unsigned short* __restrict__ AH, const unsigned short* __restrict__ AL,
                       const unsigned short* __restrict__ SWH, const unsigned short* __restrict__ SWL,
                       const float* __restrict__ bias, float* __restrict__ out, int M, int K) {
  __shared__ __align__(16) unsigned short AsH[4096];
  __shared__ __align__(16) unsigned short AsL[4096];
  __shared__ __align__(16) unsigned short BsH[8192];
  __shared__ __align__(16) unsigned short BsL[8192];
  __shared__ float smax[128 * 4];
  __shared__ float ssum[128 * 4];

  const int tid = threadIdx.x;
  const int w = tid >> 6;
  const int l = tid & 63;
  const int l15 = l & 15;
  const int quad = l >> 4;
  const int wm = w & 1;
  const int wn = w >> 1;
  const int bm = blockIdx.x * 128;
  const int ktc = K >> 5;
  const int chunksPerCb = ktc * 512;

  floatx4 acc[4][4];
#pragma unroll
  for (int i = 0; i < 4; ++i)
#pragma unroll
    for (int j = 0; j < 4; ++j) acc[i][j] = (floatx4){0.f, 0.f, 0.f, 0.f};

  for (int kt = 0; kt < ktc; ++kt) {
    __syncthreads();

    {
      int L = tid;
      int row = L >> 2;
      int p = L & 3;
      int kc = p ^ (row & 3) ^ ((row >> 2) & 3);
      int grow = bm + row;
      if (grow > M - 1) grow = M - 1;
      const unsigned short* gH = AH + (size_t)grow * K + kt * 32 + kc * 8;
      const unsigned short* gL = AL + (size_t)grow * K + kt * 32 + kc * 8;
      __builtin_amdgcn_global_load_lds(AS1C(gH), AS3(&AsH[(w * 64) * 8]), 16, 0, 0);
      __builtin_amdgcn_global_load_lds(AS1C(gL), AS3(&AsL[(w * 64) * 8]), 16, 0, 0);
    }
#pragma unroll
    for (int j = 0; j < 2; ++j) {
      int pos = j * 512 + w * 64 + l;
      int kc = pos >> 8;
      int within = pos & 255;
      int cb = within >> 7;
      int colL = within & 127;
      size_t gi = (size_t)cb * chunksPerCb + (size_t)kt * 512 + kc * 128 + colL;
      __builtin_amdgcn_global_load_lds(AS1C(SWH + gi * 8),
                                       AS3(&BsH[(j * 512 + w * 64) * 8]), 16, 0, 0);
      __builtin_amdgcn_global_load_lds(AS1C(SWL + gi * 8),
                                       AS3(&BsL[(j * 512 + w * 64) * 8]), 16, 0, 0);
    }

    __syncthreads();

    bf16x8 aH[4], aL[4];
#pragma unroll
    for (int fi = 0; fi < 4; ++fi) {
      int r = wm * 64 + fi * 16 + l15;
      int sw = quad ^ (r & 3) ^ ((r >> 2) & 3);
      aH[fi] = *(const bf16x8*)&AsH[(r * 4 + sw) * 8];
      aL[fi] = *(const bf16x8*)&AsL[(r * 4 + sw) * 8];
    }
#pragma unroll
    for (int fj = 0; fj < 4; ++fj) {
      int colG = wn * 64 + fj * 16 + l15;
      int cidx = quad * 256 + colG;
      bf16x8 bh = *(const bf16x8*)&BsH[cidx * 8];
      bf16x8 bl = *(const bf16x8*)&BsL[cidx * 8];
#pragma unroll
      for (int fi = 0; fi < 4; ++fi) {
        floatx4 t = acc[fi][fj];
        t = __builtin_amdgcn_mfma_f32_16x16x32_bf16(aH[fi], bl, t, 0, 0, 0);
        t = __builtin_amdgcn_mfma_f32_16x16x32_bf16(aL[fi], bh, t, 0, 0, 0);
        t = __builtin_amdgcn_mfma_f32_16x16x32_bf16(aH[fi], bh, t, 0, 0, 0);
        acc[fi][fj] = t;
      }
    }
  }

  float bcol[4];
#pragma unroll
  for (int fj = 0; fj < 4; ++fj)
    bcol[fj] = bias[wn * 64 + fj * 16 + l15];

#pragma unroll
  for (int fi = 0; fi < 4; ++fi) {
#pragma unroll
    for (int r = 0; r < 4; ++r) {
      float mv = -3.4e38f;
#pragma unroll
      for (int fj = 0; fj < 4; ++fj) mv = fmaxf(mv, acc[fi][fj][r] + bcol[fj]);
#pragma unroll
      for (int off = 1; off < 16; off <<= 1) mv = fmaxf(mv, __shfl_xor(mv, off));
      int row = wm * 64 + fi * 16 + quad * 4 + r;
      if (l15 == 0) smax[row * 4 + wn] = mv;
    }
  }
  __syncthreads();

#pragma unroll
  for (int fi = 0; fi < 4; ++fi) {
#pragma unroll
    for (int r = 0; r < 4; ++r) {
      int row = wm * 64 + fi * 16 + quad * 4 + r;
      float gm = fmaxf(fmaxf(smax[row * 4 + 0], smax[row * 4 + 1]),
                       fmaxf(smax[row * 4 + 2], smax[row * 4 + 3]));
      float s = 0.f;
#pragma unroll
      for (int fj = 0; fj < 4; ++fj) {
        float p = expf(acc[fi][fj][r] + bcol[fj] - gm);
        acc[fi][fj][r] = p;
        s += p;
      }
#pragma unroll
      for (int off = 1; off < 16; off <<= 1) s += __shfl_xor(s, off);
      if (l15 == 0) ssum[row * 4 + wn] = s;
    }
  }
  __syncthreads();

#pragma unroll
  for (int fi = 0; fi < 4; ++fi) {
#pragma unroll
    for (int r = 0; r < 4; ++r) {
      int row = wm * 64 + fi * 16 + quad * 4 + r;
      int grow = bm + row;
      if (grow < M) {
        float inv = 1.0f / (ssum[row * 4 + 0] + ssum[row * 4 + 1] +
                            ssum[row * 4 + 2] + ssum[row * 4 + 3]);
        float* Cp = out + (size_t)grow * HDIM + wn * 64 + l15;
#pragma unroll
        for (int fj = 0; fj < 4; ++fj) Cp[fj * 16] = acc[fi][fj][r] * inv;
      }
    }
  }
}

// ---------------- GCN aggregation: persistent waves + DYNAMIC work queue ----------------
// r2 (short blocks, CP-scheduled): 54.5us, occupancy ~50% (turnover).
// r3 (persistent, static stride):  59.7us (imbalance).
// Now: residency-sized grid (2048 blk = 32 waves/CU), each wave pulls its next
// row from a global atomic cursor -> no turnover AND balanced.

__global__ __launch_bounds__(256)
void aggregate_q(const float* __restrict__ t, const float* __restrict__ dinv,
                 const int* __restrict__ rowptr, const int* __restrict__ col,
                 const float* __restrict__ wsrc, const float* __restrict__ bias,
                 unsigned short* __restrict__ OH, unsigned short* __restrict__ OL,
                 int* __restrict__ qcur, int n) {
  const int lane = threadIdx.x & 63;
  float4 bb = ((const float4*)bias)[lane];

  for (;;) {
    int gw = 0;
    if (lane == 0) gw = atomicAdd(qcur, 1);
    gw = __shfl(gw, 0);
    if (gw >= n) break;

    float di = dinv[gw];
    float4 v = ((const float4*)(t + (size_t)gw * HDIM))[lane];
    float ss = di * di;
    float a0 = v.x * ss, a1 = v.y * ss, a2 = v.z * ss, a3 = v.w * ss;
    int e0 = rowptr[gw], e1 = rowptr[gw + 1];

    for (int base = e0; base < e1; base += 8) {
      int cs[8];
      float wv[8];
#pragma unroll
      for (int i = 0; i < 8; ++i) {
        int e = base + i;
        if (e > e1 - 1) e = e1 - 1;
        cs[i] = col[e];
        wv[i] = wsrc[e];
      }
      float wg[8];
#pragma unroll
      for (int i = 0; i < 8; ++i)
        wg[i] = (base + i < e1) ? wv[i] * di : 0.f;
      float4 rw[8];
#pragma unroll
      for (int i = 0; i < 8; ++i)
        rw[i] = ((const float4*)(t + (size_t)cs[i] * HDIM))[lane];
#pragma unroll
      for (int i = 0; i < 8; ++i) {
        a0 = fmaf(rw[i].x, wg[i], a0);
        a1 = fmaf(rw[i].y, wg[i], a1);
        a2 = fmaf(rw[i].z, wg[i], a2);
        a3 = fmaf(rw[i].w, wg[i], a3);
      }
    }

    float r0 = fmaxf(a0 + bb.x, 0.f);
    float r1 = fmaxf(a1 + bb.y, 0.f);
    float r2 = fmaxf(a2 + bb.z, 0.f);
    float r3 = fmaxf(a3 + bb.w, 0.f);
    unsigned short h0, h1, h2, h3, l0, l1, l2, l3;
    split_f32(r0, h0, l0);
    split_f32(r1, h1, l1);
    split_f32(r2, h2, l2);
    split_f32(r3, h3, l3);
    ((ushortx4*)(OH + (size_t)gw * HDIM))[lane] = (ushortx4){h0, h1, h2, h3};
    ((ushortx4*)(OL + (size_t)gw * HDIM))[lane] = (ushortx4){l0, l1, l2, l3};
  }
}

// ---------------- launch ----------------

extern "C" void kernel_launch(void* const* d_in, const int* in_sizes, int n_in,
                              void* d_out, int out_size, void* d_ws, size_t ws_size,
                              hipStream_t stream) {
  const float* x   = (const float*)d_in[0];
  const int*   ei  = (const int*)d_in[1];
  const float* W1  = (const float*)d_in[2];
  const float* b1  = (const float*)d_in[3];
  const float* Wg1 = (const float*)d_in[4];
  const float* bg1 = (const float*)d_in[5];
  const float* Wg2 = (const float*)d_in[6];
  const float* bg2 = (const float*)d_in[7];
  const float* W2  = (const float*)d_in[8];
  const float* b2  = (const float*)d_in[9];
  const float* W3  = (const float*)d_in[10];
  const float* b3  = (const float*)d_in[11];
  float* out = (float*)d_out;

  const int K1 = in_sizes[2] / HDIM;  // 128
  const int N  = in_sizes[0] / K1;    // 50000
  const int E  = in_sizes[1] / 2;     // 300000

  char* w = (char*)d_ws;
  auto alloc = [&](size_t bytes) -> char* {
    char* p = w;
    w += (bytes + 255) & ~(size_t)255;
    return p;
  };
  unsigned short* PH = (unsigned short*)alloc((size_t)N * HDIM * 2);
  unsigned short* PL = (unsigned short*)alloc((size_t)N * HDIM * 2);
  float* dinv   = (float*)alloc((size_t)N * sizeof(float));
  int*   deg    = (int*)alloc((size_t)N * sizeof(int));
  int*   rowptr = (int*)alloc((size_t)(N + 1) * sizeof(int));
  int*   cursor = (int*)alloc((size_t)N * sizeof(int));
  int*   col    = (int*)alloc((size_t)E * sizeof(int));
  float* wcsr   = (float*)alloc((size_t)E * sizeof(float));
  int*   qcur   = (int*)alloc(2 * sizeof(int));
  const int nb  = (N + 255) / 256;
  int*   bsum   = (int*)alloc((size_t)nb * sizeof(int));
  int*   boff   = (int*)alloc((size_t)nb * sizeof(int));
  unsigned short* W1sH  = (unsigned short*)alloc((size_t)HDIM * K1 * 2);
  unsigned short* W1sL  = (unsigned short*)alloc((size_t)HDIM * K1 * 2);
  unsigned short* Wg1sH = (unsigned short*)alloc((size_t)HDIM * HDIM * 2);
  unsigned short* Wg1sL = (unsigned short*)alloc((size_t)HDIM * HDIM * 2);
  unsigned short* Wg2sH = (unsigned short*)alloc((size_t)HDIM * HDIM * 2);
  unsigned short* Wg2sL = (unsigned short*)alloc((size_t)HDIM * HDIM * 2);
  unsigned short* W2sH  = (unsigned short*)alloc((size_t)HDIM * HDIM * 2);
  unsigned short* W2sL  = (unsigned short*)alloc((size_t)HDIM * HDIM * 2);
  unsigned short* W3sH  = (unsigned short*)alloc((size_t)HDIM * HDIM * 2);
  unsigned short* W3sL  = (unsigned short*)alloc((size_t)HDIM * HDIM * 2);

  const int ge = (E + 255) / 256;

  const int prepChunks = K1 * 32 + 4 * HDIM * 32;
  prep_w_all<<<(prepChunks + 255) / 256, 256, 0, stream>>>(
      W1, W1sH, W1sL, K1, Wg1, Wg1sH, Wg1sL, Wg2, Wg2sH, Wg2sL,
      W2, W2sH, W2sL, W3, W3sH, W3sL);

  hipMemsetAsync(deg, 0, (size_t)N * sizeof(int), stream);
  hipMemsetAsync(qcur, 0, 2 * sizeof(int), stream);
  deg_count_kernel<<<ge, 256, 0, stream>>>(ei, deg, E);
  block_sum_kernel<<<nb, 256, 0, stream>>>(deg, bsum, dinv, N);
  scan_bsums_kernel<<<1, 256, 0, stream>>>(bsum, boff, rowptr, nb, N);
  scan_final_kernel<<<nb, 256, 0, stream>>>(deg, boff, rowptr, cursor, N);
  fill_csr_kernel<<<ge, 256, 0, stream>>>(ei, dinv, cursor, col, wcsr, E);

  const int g128 = (N + 127) / 128;
  const int gq = 2048;  // exact residency: 8 blocks/CU x 256 CUs (VGPR<=64)

  // h0 = relu(x@W1+b1) -> planes P (fp32 A split fused in-kernel)
  mfma_gemm_sA<true, true><<<g128, 512, 0, stream>>>(x, W1sH, W1sL, b1, PH, PL, N, K1);
  // t1 = h0@Wg1 -> out (fp32 scratch in d_out)
  mfma_gemm_p<false, false, false><<<g128, 512, 0, stream>>>(PH, PL, Wg1sH, Wg1sL, nullptr, out, nullptr, nullptr, N, HDIM);
  // h1 = relu(agg(t1)+bg1) -> planes P
  aggregate_q<<<gq, 256, 0, stream>>>(out, dinv, rowptr, col, wcsr, bg1, PH, PL, qcur + 0, N);
  // t2 = h1@Wg2 -> out
  mfma_gemm_p<false, false, false><<<g128, 512, 0, stream>>>(PH, PL, Wg2sH, Wg2sL, nullptr, out, nullptr, nullptr, N, HDIM);
  // h2 = relu(agg(t2)+bg2) -> planes P
  aggregate_q<<<gq, 256, 0, stream>>>(out, dinv, rowptr, col, wcsr, bg2, PH, PL, qcur + 1, N);
  // h3 = relu(h2@W2+b2) -> planes P IN-PLACE (safe: per-block panel ownership)
  mfma_gemm_p<true, true, true><<<g128, 512, 0, stream>>>(PH, PL, W2sH, W2sL, b2, nullptr, PH, PL, N, HDIM);
  // out = softmax(h3@W3+b3): reads ws planes, writes d_out (disjoint)
  mfma_gemm_softmax<<<g128, 512, 0, stream>>>(PH, PL, W3sH, W3sL, b3, out, N, HDIM);
}

// Round 9
// 540.685 us; speedup vs baseline: 3.0224x; 3.0224x over previous
//
#include <hip/hip_runtime.h>
#include <math.h>

#define HDIM 256

typedef float floatx4 __attribute__((ext_vector_type(4)));
typedef __bf16 bf16x8 __attribute__((ext_vector_type(8)));
typedef unsigned short ushortx4 __attribute__((ext_vector_type(4)));
typedef unsigned short ushortx8 __attribute__((ext_vector_type(8)));

#define AS1C(p) ((const __attribute__((address_space(1))) void*)(p))
#define AS3(p)  ((__attribute__((address_space(3))) void*)(p))

__device__ inline unsigned short bf16_rn(float f) {
  unsigned u = __float_as_uint(f);
  return (unsigned short)((u + 0x7FFFu + ((u >> 16) & 1u)) >> 16);
}

__device__ inline void split_f32(float f, unsigned short& h, unsigned short& l) {
  unsigned short hb = bf16_rn(f);
  float hf = __uint_as_float(((unsigned)hb) << 16);
  h = hb;
  l = bf16_rn(f - hf);
}

// ---------------- weight prep: all 5 weights in ONE launch ----------------

__device__ inline void prep_w_body(const float* __restrict__ W,
                                   unsigned short* __restrict__ SH,
                                   unsigned short* __restrict__ SL, int K, int idx) {
  int total = K * 32;
  int chunksPerCb = total >> 1;
  int cb = (idx >= chunksPerCb) ? 1 : 0;
  int rem = idx - cb * chunksPerCb;
  int kt = rem >> 9;
  int chunk = rem & 511;
  int kc = chunk >> 7;
  int col = chunk & 127;
  const float* src = W + (size_t)(kt * 32 + kc * 8) * HDIM + cb * 128 + col;
#pragma unroll
  for (int e = 0; e < 8; ++e) {
    unsigned short h, l;
    split_f32(src[(size_t)e * HDIM], h, l);
    SH[(size_t)idx * 8 + e] = h;
    SL[(size_t)idx * 8 + e] = l;
  }
}

__global__ __launch_bounds__(256)
void prep_w_all(const float* __restrict__ W1, unsigned short* __restrict__ S1H,
                unsigned short* __restrict__ S1L, int K1,
                const float* __restrict__ Wg1, unsigned short* __restrict__ G1H,
                unsigned short* __restrict__ G1L,
                const float* __restrict__ Wg2, unsigned short* __restrict__ G2H,
                unsigned short* __restrict__ G2L,
                const float* __restrict__ W2, unsigned short* __restrict__ S2H,
                unsigned short* __restrict__ S2L,
                const float* __restrict__ W3, unsigned short* __restrict__ S3H,
                unsigned short* __restrict__ S3L) {
  int gidx = blockIdx.x * 256 + threadIdx.x;
  int t1 = K1 * 32;
  int t256 = HDIM * 32;
  if (gidx < t1) {
    prep_w_body(W1, S1H, S1L, K1, gidx);
    return;
  }
  int r = gidx - t1;
  int which = r / t256;
  int idx = r - which * t256;
  if (which == 0)      prep_w_body(Wg1, G1H, G1L, HDIM, idx);
  else if (which == 1) prep_w_body(Wg2, G2H, G2L, HDIM, idx);
  else if (which == 2) prep_w_body(W2, S2H, S2L, HDIM, idx);
  else if (which == 3) prep_w_body(W3, S3H, S3L, HDIM, idx);
}

// ---------------- CSR build ----------------

__global__ __launch_bounds__(256)
void deg_count_kernel(const int* __restrict__ ei, int* __restrict__ deg, int E) {
  int e = blockIdx.x * 256 + threadIdx.x;
  if (e < E) atomicAdd(&deg[ei[E + e]], 1);
}

__global__ __launch_bounds__(256)
void block_sum_kernel(const int* __restrict__ deg, int* __restrict__ bsum,
                      float* __restrict__ dinv, int n) {
  __shared__ int sm[256];
  int t = threadIdx.x;
  int idx = blockIdx.x * 256 + t;
  int v = (idx < n) ? deg[idx] : 0;
  sm[t] = v;
  if (idx < n) dinv[idx] = 1.0f / sqrtf((float)v + 1.0f);
  __syncthreads();
  for (int off = 128; off > 0; off >>= 1) {
    if (t < off) sm[t] += sm[t + off];
    __syncthreads();
  }
  if (t == 0) bsum[blockIdx.x] = sm[0];
}

__global__ __launch_bounds__(256)
void scan_bsums_kernel(const int* __restrict__ bsum, int* __restrict__ boff,
                       int* __restrict__ rowptr, int nb, int n) {
  __shared__ int sm[256];
  int t = threadIdx.x;
  int v = (t < nb) ? bsum[t] : 0;
  sm[t] = v;
  __syncthreads();
  for (int off = 1; off < 256; off <<= 1) {
    int a = (t >= off) ? sm[t - off] : 0;
    __syncthreads();
    sm[t] += a;
    __syncthreads();
  }
  if (t < nb) boff[t] = sm[t] - v;
  if (t == 255) rowptr[n] = sm[255];
}

__global__ __launch_bounds__(256)
void scan_final_kernel(const int* __restrict__ deg, const int* __restrict__ boff,
                       int* __restrict__ rowptr, int* __restrict__ cursor, int n) {
  __shared__ int sm[256];
  int t = threadIdx.x;
  int idx = blockIdx.x * 256 + t;
  int v = (idx < n) ? deg[idx] : 0;
  sm[t] = v;
  __syncthreads();
  for (int off = 1; off < 256; off <<= 1) {
    int a = (t >= off) ? sm[t - off] : 0;
    __syncthreads();
    sm[t] += a;
    __syncthreads();
  }
  int excl = sm[t] - v + boff[blockIdx.x];
  if (idx < n) { rowptr[idx] = excl; cursor[idx] = excl; }
}

__global__ __launch_bounds__(256)
void fill_csr_kernel(const int* __restrict__ ei, const float* __restrict__ dinv,
                     int* __restrict__ cursor, int* __restrict__ col,
                     float* __restrict__ wsrc, int E) {
  int e = blockIdx.x * 256 + threadIdx.x;
  if (e < E) {
    int s = ei[e];
    int d = ei[E + e];
    int p = atomicAdd(&cursor[d], 1);
    col[p] = s;
    wsrc[p] = dinv[s];
  }
}

// ---------------- fused double-GEMM: (A@W1+b1 -> relu) @ W2 [+b2 -> softmax] ----------------
// Tile 128 rows x FULL 256 cols => each block owns complete intermediate rows.
// Phase 1 = proven 128x256 GEMM body; intermediate never touches HBM: per
// 32-col slice kt2, the 2 waves owning those cols (wn==kt2>>1) relu+split and
// ds_write into the SAME swizzled LDS layout the stage path uses (chunk
// (R*4 + (kc ^ swz(R)))*8 + e). Phase 2 = standard MFMA loop over the slices.
// Saves 51MB write + 51MB read of intermediate planes per fused pair.

template<bool P1F32, bool SOFTMX>
__global__ __launch_bounds__(512, 2)
void fused_gemm2(const float* __restrict__ A32,
                 const unsigned short* __restrict__ APH, const unsigned short* __restrict__ APL,
                 const unsigned short* __restrict__ SW1H, const unsigned short* __restrict__ SW1L,
                 const float* __restrict__ bias1,
                 const unsigned short* __restrict__ SW2H, const unsigned short* __restrict__ SW2L,
                 const float* __restrict__ bias2,
                 float* __restrict__ outC, int M, int K1) {
  __shared__ __align__(16) unsigned short AsH[4096];
  __shared__ __align__(16) unsigned short AsL[4096];
  __shared__ __align__(16) unsigned short BsH[8192];
  __shared__ __align__(16) unsigned short BsL[8192];
  __shared__ float smax[128 * 4];
  __shared__ float ssum[128 * 4];

  const int tid = threadIdx.x;
  const int w = tid >> 6;
  const int l = tid & 63;
  const int l15 = l & 15;
  const int quad = l >> 4;
  const int wm = w & 1;
  const int wn = w >> 1;
  const int bm = blockIdx.x * 128;
  const int ktc1 = K1 >> 5;
  const int cPc1 = ktc1 * 512;

  floatx4 acc1[4][4];
#pragma unroll
  for (int i = 0; i < 4; ++i)
#pragma unroll
    for (int j = 0; j < 4; ++j) acc1[i][j] = (floatx4){0.f, 0.f, 0.f, 0.f};

  // A geometry for fp32 path
  const int arow = tid >> 2;
  const int ap = tid & 3;
  const int akc = ap ^ (arow & 3) ^ ((arow >> 2) & 3);
  int agrow = bm + arow;
  if (agrow > M - 1) agrow = M - 1;
  const float* agp = P1F32 ? (A32 + (size_t)agrow * K1 + akc * 8) : nullptr;

  // ---- phase 1 ----
  for (int kt = 0; kt < ktc1; ++kt) {
    float4 f0, f1;
    if (P1F32) {
      f0 = *(const float4*)(agp + kt * 32);
      f1 = *(const float4*)(agp + kt * 32 + 4);
    }

    __syncthreads();

#pragma unroll
    for (int j = 0; j < 2; ++j) {
      int pos = j * 512 + w * 64 + l;
      int kc = pos >> 8;
      int within = pos & 255;
      int cb = within >> 7;
      int colL = within & 127;
      size_t gi = (size_t)cb * cPc1 + (size_t)kt * 512 + kc * 128 + colL;
      __builtin_amdgcn_global_load_lds(AS1C(SW1H + gi * 8),
                                       AS3(&BsH[(j * 512 + w * 64) * 8]), 16, 0, 0);
      __builtin_amdgcn_global_load_lds(AS1C(SW1L + gi * 8),
                                       AS3(&BsL[(j * 512 + w * 64) * 8]), 16, 0, 0);
    }

    if (P1F32) {
      float f[8] = {f0.x, f0.y, f0.z, f0.w, f1.x, f1.y, f1.z, f1.w};
      ushortx8 hh, ll;
#pragma unroll
      for (int e = 0; e < 8; ++e) {
        unsigned short h, lo;
        split_f32(f[e], h, lo);
        hh[e] = h;
        ll[e] = lo;
      }
      *(ushortx8*)&AsH[(size_t)tid * 8] = hh;
      *(ushortx8*)&AsL[(size_t)tid * 8] = ll;
    } else {
      int row = tid >> 2;
      int p = tid & 3;
      int kc = p ^ (row & 3) ^ ((row >> 2) & 3);
      int grow = bm + row;
      if (grow > M - 1) grow = M - 1;
      const unsigned short* gH = APH + (size_t)grow * K1 + kt * 32 + kc * 8;
      const unsigned short* gL = APL + (size_t)grow * K1 + kt * 32 + kc * 8;
      __builtin_amdgcn_global_load_lds(AS1C(gH), AS3(&AsH[(w * 64) * 8]), 16, 0, 0);
      __builtin_amdgcn_global_load_lds(AS1C(gL), AS3(&AsL[(w * 64) * 8]), 16, 0, 0);
    }

    __syncthreads();

    bf16x8 aH[4], aL[4];
#pragma unroll
    for (int fi = 0; fi < 4; ++fi) {
      int r = wm * 64 + fi * 16 + l15;
      int sw = quad ^ (r & 3) ^ ((r >> 2) & 3);
      aH[fi] = *(const bf16x8*)&AsH[(r * 4 + sw) * 8];
      aL[fi] = *(const bf16x8*)&AsL[(r * 4 + sw) * 8];
    }
#pragma unroll
    for (int fj = 0; fj < 4; ++fj) {
      int colG = wn * 64 + fj * 16 + l15;
      int cidx = quad * 256 + colG;
      bf16x8 bh = *(const bf16x8*)&BsH[cidx * 8];
      bf16x8 bl = *(const bf16x8*)&BsL[cidx * 8];
#pragma unroll
      for (int fi = 0; fi < 4; ++fi) {
        floatx4 t = acc1[fi][fj];
        t = __builtin_amdgcn_mfma_f32_16x16x32_bf16(aH[fi], bl, t, 0, 0, 0);
        t = __builtin_amdgcn_mfma_f32_16x16x32_bf16(aL[fi], bh, t, 0, 0, 0);
        t = __builtin_amdgcn_mfma_f32_16x16x32_bf16(aH[fi], bh, t, 0, 0, 0);
        acc1[fi][fj] = t;
      }
    }
  }

  float bcol1[4];
#pragma unroll
  for (int fj = 0; fj < 4; ++fj)
    bcol1[fj] = bias1[wn * 64 + fj * 16 + l15];

  // ---- phase 2: intermediate via LDS slices ----
  floatx4 acc2[4][4];
#pragma unroll
  for (int i = 0; i < 4; ++i)
#pragma unroll
    for (int j = 0; j < 4; ++j) acc2[i][j] = (floatx4){0.f, 0.f, 0.f, 0.f};

  const int cPc2 = 8 * 512;  // phase-2 K = HDIM = 256

  for (int kt2 = 0; kt2 < 8; ++kt2) {
    __syncthreads();  // prior MFMA reads of As/Bs complete

    // owning waves write relu(acc1+b1) slice into swizzled A layout
    if (wn == (kt2 >> 1)) {
      int fjb = (kt2 & 1) * 2;
#pragma unroll
      for (int fjo = 0; fjo < 2; ++fjo) {
        int fj = fjb + fjo;
        int cl = fjo * 16 + l15;        // 0..31 within slice
        int kc = cl >> 3;
        int e = cl & 7;
#pragma unroll
        for (int fi = 0; fi < 4; ++fi) {
#pragma unroll
          for (int r = 0; r < 4; ++r) {
            int R = wm * 64 + fi * 16 + quad * 4 + r;
            int p = kc ^ (R & 3) ^ ((R >> 2) & 3);
            float v = fmaxf(acc1[fi][fj][r] + bcol1[fj], 0.f);
            unsigned short h, lo;
            split_f32(v, h, lo);
            AsH[(R * 4 + p) * 8 + e] = h;
            AsL[(R * 4 + p) * 8 + e] = lo;
          }
        }
      }
    }

    // stage phase-2 weight slice
#pragma unroll
    for (int j = 0; j < 2; ++j) {
      int pos = j * 512 + w * 64 + l;
      int kc = pos >> 8;
      int within = pos & 255;
      int cb = within >> 7;
      int colL = within & 127;
      size_t gi = (size_t)cb * cPc2 + (size_t)kt2 * 512 + kc * 128 + colL;
      __builtin_amdgcn_global_load_lds(AS1C(SW2H + gi * 8),
                                       AS3(&BsH[(j * 512 + w * 64) * 8]), 16, 0, 0);
      __builtin_amdgcn_global_load_lds(AS1C(SW2L + gi * 8),
                                       AS3(&BsL[(j * 512 + w * 64) * 8]), 16, 0, 0);
    }

    __syncthreads();

    bf16x8 aH[4], aL[4];
#pragma unroll
    for (int fi = 0; fi < 4; ++fi) {
      int r = wm * 64 + fi * 16 + l15;
      int sw = quad ^ (r & 3) ^ ((r >> 2) & 3);
      aH[fi] = *(const bf16x8*)&AsH[(r * 4 + sw) * 8];
      aL[fi] = *(const bf16x8*)&AsL[(r * 4 + sw) * 8];
    }
#pragma unroll
    for (int fj = 0; fj < 4; ++fj) {
      int colG = wn * 64 + fj * 16 + l15;
      int cidx = quad * 256 + colG;
      bf16x8 bh = *(const bf16x8*)&BsH[cidx * 8];
      bf16x8 bl = *(const bf16x8*)&BsL[cidx * 8];
#pragma unroll
      for (int fi = 0; fi < 4; ++fi) {
        floatx4 t = acc2[fi][fj];
        t = __builtin_amdgcn_mfma_f32_16x16x32_bf16(aH[fi], bl, t, 0, 0, 0);
        t = __builtin_amdgcn_mfma_f32_16x16x32_bf16(aL[fi], bh, t, 0, 0, 0);
        t = __builtin_amdgcn_mfma_f32_16x16x32_bf16(aH[fi], bh, t, 0, 0, 0);
        acc2[fi][fj] = t;
      }
    }
  }

  // ---- epilogue ----
  if (SOFTMX) {
    float bcol2[4];
#pragma unroll
    for (int fj = 0; fj < 4; ++fj)
      bcol2[fj] = bias2[wn * 64 + fj * 16 + l15];

#pragma unroll
    for (int fi = 0; fi < 4; ++fi) {
#pragma unroll
      for (int r = 0; r < 4; ++r) {
        float mv = -3.4e38f;
#pragma unroll
        for (int fj = 0; fj < 4; ++fj) mv = fmaxf(mv, acc2[fi][fj][r] + bcol2[fj]);
#pragma unroll
        for (int off = 1; off < 16; off <<= 1) mv = fmaxf(mv, __shfl_xor(mv, off));
        int row = wm * 64 + fi * 16 + quad * 4 + r;
        if (l15 == 0) smax[row * 4 + wn] = mv;
      }
    }
    __syncthreads();

#pragma unroll
    for (int fi = 0; fi < 4; ++fi) {
#pragma unroll
      for (int r = 0; r < 4; ++r) {
        int row = wm * 64 + fi * 16 + quad * 4 + r;
        float gm = fmaxf(fmaxf(smax[row * 4 + 0], smax[row * 4 + 1]),
                         fmaxf(smax[row * 4 + 2], smax[row * 4 + 3]));
        float s = 0.f;
#pragma unroll
        for (int fj = 0; fj < 4; ++fj) {
          float p = expf(acc2[fi][fj][r] + bcol2[fj] - gm);
          acc2[fi][fj][r] = p;
          s += p;
        }
#pragma unroll
        for (int off = 1; off < 16; off <<= 1) s += __shfl_xor(s, off);
        if (l15 == 0) ssum[row * 4 + wn] = s;
      }
    }
    __syncthreads();

#pragma unroll
    for (int fi = 0; fi < 4; ++fi) {
#pragma unroll
      for (int r = 0; r < 4; ++r) {
        int row = wm * 64 + fi * 16 + quad * 4 + r;
        int grow = bm + row;
        if (grow < M) {
          float inv = 1.0f / (ssum[row * 4 + 0] + ssum[row * 4 + 1] +
                              ssum[row * 4 + 2] + ssum[row * 4 + 3]);
          float* Cp = outC + (size_t)grow * HDIM + wn * 64 + l15;
#pragma unroll
          for (int fj = 0; fj < 4; ++fj) Cp[fj * 16] = acc2[fi][fj][r] * inv;
        }
      }
    }
  } else {
    // plain fp32 store, no bias (t = h @ Wg)
#pragma unroll
    for (int fi = 0; fi < 4; ++fi) {
      int rb = bm + wm * 64 + fi * 16 + quad * 4;
#pragma unroll
      for (int r = 0; r < 4; ++r) {
        int row = rb + r;
        if (row < M) {
          size_t base = (size_t)row * HDIM + wn * 64 + l15;
#pragma unroll
          for (int fj = 0; fj < 4; ++fj) outC[base + fj * 16] = acc2[fi][fj][r];
        }
      }
    }
  }
}

// ---------------- plane GEMM: tile 128x256, 512 threads, single-buffered ----------------

template<bool BIAS, bool RELU, bool SPLIT_OUT>
__global__ __launch_bounds__(512, 4)
void mfma_gemm_p(const unsigned short* __restrict__ AH, const unsigned short* __restrict__ AL,
                 const unsigned short* __restrict__ SWH, const unsigned short* __restrict__ SWL,
                 const float* __restrict__ bias,
                 float* __restrict__ C, unsigned short* __restrict__ CH,
                 unsigned short* __restrict__ CL, int M, int K) {
  __shared__ __align__(16) unsigned short AsH[4096];
  __shared__ __align__(16) unsigned short AsL[4096];
  __shared__ __align__(16) unsigned short BsH[8192];
  __shared__ __align__(16) unsigned short BsL[8192];

  const int tid = threadIdx.x;
  const int w = tid >> 6;
  const int l = tid & 63;
  const int l15 = l & 15;
  const int quad = l >> 4;
  const int wm = w & 1;
  const int wn = w >> 1;
  const int bm = blockIdx.x * 128;
  const int ktc = K >> 5;
  const int chunksPerCb = ktc * 512;

  floatx4 acc[4][4];
#pragma unroll
  for (int i = 0; i < 4; ++i)
#pragma unroll
    for (int j = 0; j < 4; ++j) acc[i][j] = (floatx4){0.f, 0.f, 0.f, 0.f};

  for (int kt = 0; kt < ktc; ++kt) {
    __syncthreads();

    {
      int L = tid;
      int row = L >> 2;
      int p = L & 3;
      int kc = p ^ (row & 3) ^ ((row >> 2) & 3);
      int grow = bm + row;
      if (grow > M - 1) grow = M - 1;
      const unsigned short* gH = AH + (size_t)grow * K + kt * 32 + kc * 8;
      const unsigned short* gL = AL + (size_t)grow * K + kt * 32 + kc * 8;
      __builtin_amdgcn_global_load_lds(AS1C(gH), AS3(&AsH[(w * 64) * 8]), 16, 0, 0);
      __builtin_amdgcn_global_load_lds(AS1C(gL), AS3(&AsL[(w * 64) * 8]), 16, 0, 0);
    }
#pragma unroll
    for (int j = 0; j < 2; ++j) {
      int pos = j * 512 + w * 64 + l;
      int kc = pos >> 8;
      int within = pos & 255;
      int cb = within >> 7;
      int colL = within & 127;
      size_t gi = (size_t)cb * chunksPerCb + (size_t)kt * 512 + kc * 128 + colL;
      __builtin_amdgcn_global_load_lds(AS1C(SWH + gi * 8),
                                       AS3(&BsH[(j * 512 + w * 64) * 8]), 16, 0, 0);
      __builtin_amdgcn_global_load_lds(AS1C(SWL + gi * 8),
                                       AS3(&BsL[(j * 512 + w * 64) * 8]), 16, 0, 0);
    }

    __syncthreads();

    bf16x8 aH[4], aL[4];
#pragma unroll
    for (int fi = 0; fi < 4; ++fi) {
      int r = wm * 64 + fi * 16 + l15;
      int sw = quad ^ (r & 3) ^ ((r >> 2) & 3);
      aH[fi] = *(const bf16x8*)&AsH[(r * 4 + sw) * 8];
      aL[fi] = *(const bf16x8*)&AsL[(r * 4 + sw) * 8];
    }
#pragma unroll
    for (int fj = 0; fj < 4; ++fj) {
      int colG = wn * 64 + fj * 16 + l15;
      int cidx = quad * 256 + colG;
      bf16x8 bh = *(const bf16x8*)&BsH[cidx * 8];
      bf16x8 bl = *(const bf16x8*)&BsL[cidx * 8];
#pragma unroll
      for (int fi = 0; fi < 4; ++fi) {
        floatx4 t = acc[fi][fj];
        t = __builtin_amdgcn_mfma_f32_16x16x32_bf16(aH[fi], bl, t, 0, 0, 0);
        t = __builtin_amdgcn_mfma_f32_16x16x32_bf16(aL[fi], bh, t, 0, 0, 0);
        t = __builtin_amdgcn_mfma_f32_16x16x32_bf16(aH[fi], bh, t, 0, 0, 0);
        acc[fi][fj] = t;
      }
    }
  }

  float bcol[4];
#pragma unroll
  for (int fj = 0; fj < 4; ++fj)
    bcol[fj] = BIAS ? bias[wn * 64 + fj * 16 + l15] : 0.f;

#pragma unroll
  for (int fi = 0; fi < 4; ++fi) {
    int rb = bm + wm * 64 + fi * 16 + quad * 4;
#pragma unroll
    for (int r = 0; r < 4; ++r) {
      int row = rb + r;
      if (row < M) {
        size_t base = (size_t)row * HDIM + wn * 64 + l15;
        if (SPLIT_OUT) {
#pragma unroll
          for (int fj = 0; fj < 4; ++fj) {
            float v = acc[fi][fj][r] + bcol[fj];
            if (RELU) v = fmaxf(v, 0.f);
            unsigned short h, lo;
            split_f32(v, h, lo);
            CH[base + fj * 16] = h;
            CL[base + fj * 16] = lo;
          }
        } else {
#pragma unroll
          for (int fj = 0; fj < 4; ++fj) {
            float v = acc[fi][fj][r] + bcol[fj];
            if (RELU) v = fmaxf(v, 0.f);
            C[base + fj * 16] = v;
          }
        }
      }
    }
  }
}

// ---------------- GCN aggregation: two-phase batched gather, one row per wave ----------------
// r2-proven form (54.5us); launched as two half-row dispatches so GEMM-class
// kernels surface in the rocprof top-5 (diagnostic; ~neutral cost).

__global__ __launch_bounds__(256)
void aggregate_b(const float* __restrict__ t, const float* __restrict__ dinv,
                 const int* __restrict__ rowptr, const int* __restrict__ col,
                 const float* __restrict__ wsrc, const float* __restrict__ bias,
                 unsigned short* __restrict__ OH, unsigned short* __restrict__ OL,
                 int row0, int nend) {
  int gw = row0 + (int)((blockIdx.x * 256 + threadIdx.x) >> 6);
  int lane = threadIdx.x & 63;
  if (gw >= nend) return;
  float di = dinv[gw];
  float4 v = ((const float4*)(t + (size_t)gw * HDIM))[lane];
  float ss = di * di;
  float a0 = v.x * ss, a1 = v.y * ss, a2 = v.z * ss, a3 = v.w * ss;
  int e0 = rowptr[gw], e1 = rowptr[gw + 1];

  for (int base = e0; base < e1; base += 8) {
    int cs[8];
    float wv[8];
#pragma unroll
    for (int i = 0; i < 8; ++i) {
      int e = base + i;
      if (e > e1 - 1) e = e1 - 1;
      cs[i] = col[e];
      wv[i] = wsrc[e];
    }
    float wg[8];
#pragma unroll
    for (int i = 0; i < 8; ++i)
      wg[i] = (base + i < e1) ? wv[i] * di : 0.f;
    float4 rw[8];
#pragma unroll
    for (int i = 0; i < 8; ++i)
      rw[i] = ((const float4*)(t + (size_t)cs[i] * HDIM))[lane];
#pragma unroll
    for (int i = 0; i < 8; ++i) {
      a0 = fmaf(rw[i].x, wg[i], a0);
      a1 = fmaf(rw[i].y, wg[i], a1);
      a2 = fmaf(rw[i].z, wg[i], a2);
      a3 = fmaf(rw[i].w, wg[i], a3);
    }
  }

  float4 bb = ((const float4*)bias)[lane];
  float r0 = fmaxf(a0 + bb.x, 0.f);
  float r1 = fmaxf(a1 + bb.y, 0.f);
  float r2 = fmaxf(a2 + bb.z, 0.f);
  float r3 = fmaxf(a3 + bb.w, 0.f);
  unsigned short h0, h1, h2, h3, l0, l1, l2, l3;
  split_f32(r0, h0, l0);
  split_f32(r1, h1, l1);
  split_f32(r2, h2, l2);
  split_f32(r3, h3, l3);
  ((ushortx4*)(OH + (size_t)gw * HDIM))[lane] = (ushortx4){h0, h1, h2, h3};
  ((ushortx4*)(OL + (size_t)gw * HDIM))[lane] = (ushortx4){l0, l1, l2, l3};
}

// ---------------- launch ----------------

extern "C" void kernel_launch(void* const* d_in, const int* in_sizes, int n_in,
                              void* d_out, int out_size, void* d_ws, size_t ws_size,
                              hipStream_t stream) {
  const float* x   = (const float*)d_in[0];
  const int*   ei  = (const int*)d_in[1];
  const float* W1  = (const float*)d_in[2];
  const float* b1  = (const float*)d_in[3];
  const float* Wg1 = (const float*)d_in[4];
  const float* bg1 = (const float*)d_in[5];
  const float* Wg2 = (const float*)d_in[6];
  const float* bg2 = (const float*)d_in[7];
  const float* W2  = (const float*)d_in[8];
  const float* b2  = (const float*)d_in[9];
  const float* W3  = (const float*)d_in[10];
  const float* b3  = (const float*)d_in[11];
  float* out = (float*)d_out;

  const int K1 = in_sizes[2] / HDIM;  // 128
  const int N  = in_sizes[0] / K1;    // 50000
  const int E  = in_sizes[1] / 2;     // 300000

  char* w = (char*)d_ws;
  auto alloc = [&](size_t bytes) -> char* {
    char* p = w;
    w += (bytes + 255) & ~(size_t)255;
    return p;
  };
  unsigned short* PH = (unsigned short*)alloc((size_t)N * HDIM * 2);
  unsigned short* PL = (unsigned short*)alloc((size_t)N * HDIM * 2);
  float* dinv   = (float*)alloc((size_t)N * sizeof(float));
  int*   deg    = (int*)alloc((size_t)N * sizeof(int));
  int*   rowptr = (int*)alloc((size_t)(N + 1) * sizeof(int));
  int*   cursor = (int*)alloc((size_t)N * sizeof(int));
  int*   col    = (int*)alloc((size_t)E * sizeof(int));
  float* wcsr   = (float*)alloc((size_t)E * sizeof(float));
  const int nb  = (N + 255) / 256;
  int*   bsum   = (int*)alloc((size_t)nb * sizeof(int));
  int*   boff   = (int*)alloc((size_t)nb * sizeof(int));
  unsigned short* W1sH  = (unsigned short*)alloc((size_t)HDIM * K1 * 2);
  unsigned short* W1sL  = (unsigned short*)alloc((size_t)HDIM * K1 * 2);
  unsigned short* Wg1sH = (unsigned short*)alloc((size_t)HDIM * HDIM * 2);
  unsigned short* Wg1sL = (unsigned short*)alloc((size_t)HDIM * HDIM * 2);
  unsigned short* Wg2sH = (unsigned short*)alloc((size_t)HDIM * HDIM * 2);
  unsigned short* Wg2sL = (unsigned short*)alloc((size_t)HDIM * HDIM * 2);
  unsigned short* W2sH  = (unsigned short*)alloc((size_t)HDIM * HDIM * 2);
  unsigned short* W2sL  = (unsigned short*)alloc((size_t)HDIM * HDIM * 2);
  unsigned short* W3sH  = (unsigned short*)alloc((size_t)HDIM * HDIM * 2);
  unsigned short* W3sL  = (unsigned short*)alloc((size_t)HDIM * HDIM * 2);

  const int ge = (E + 255) / 256;

  const int prepChunks = K1 * 32 + 4 * HDIM * 32;
  prep_w_all<<<(prepChunks + 255) / 256, 256, 0, stream>>>(
      W1, W1sH, W1sL, K1, Wg1, Wg1sH, Wg1sL, Wg2, Wg2sH, Wg2sL,
      W2, W2sH, W2sL, W3, W3sH, W3sL);

  hipMemsetAsync(deg, 0, (size_t)N * sizeof(int), stream);
  deg_count_kernel<<<ge, 256, 0, stream>>>(ei, deg, E);
  block_sum_kernel<<<nb, 256, 0, stream>>>(deg, bsum, dinv, N);
  scan_bsums_kernel<<<1, 256, 0, stream>>>(bsum, boff, rowptr, nb, N);
  scan_final_kernel<<<nb, 256, 0, stream>>>(deg, boff, rowptr, cursor, N);
  fill_csr_kernel<<<ge, 256, 0, stream>>>(ei, dinv, cursor, col, wcsr, E);

  const int g128 = (N + 127) / 128;
  const int half = (N + 1) / 2;
  const int gagg1 = (half + 3) / 4;
  const int gagg2 = (N - half + 3) / 4;

  // t1 = relu(x@W1+b1) @ Wg1 -> out  (fused: h0 never hits HBM)
  fused_gemm2<true, false><<<g128, 512, 0, stream>>>(
      x, nullptr, nullptr, W1sH, W1sL, b1, Wg1sH, Wg1sL, nullptr, out, N, K1);
  // h1 = relu(agg(t1)+bg1) -> planes P  (two halves: diagnostic split)
  aggregate_b<<<gagg1, 256, 0, stream>>>(out, dinv, rowptr, col, wcsr, bg1, PH, PL, 0, half);
  aggregate_b<<<gagg2, 256, 0, stream>>>(out, dinv, rowptr, col, wcsr, bg1, PH, PL, half, N);
  // t2 = h1@Wg2 -> out
  mfma_gemm_p<false, false, false><<<g128, 512, 0, stream>>>(PH, PL, Wg2sH, Wg2sL, nullptr, out, nullptr, nullptr, N, HDIM);
  // h2 = relu(agg(t2)+bg2) -> planes P
  aggregate_b<<<gagg1, 256, 0, stream>>>(out, dinv, rowptr, col, wcsr, bg2, PH, PL, 0, half);
  aggregate_b<<<gagg2, 256, 0, stream>>>(out, dinv, rowptr, col, wcsr, bg2, PH, PL, half, N);
  // out = softmax(relu(h2@W2+b2)@W3+b3)  (fused: h3 never hits HBM)
  fused_gemm2<false, true><<<g128, 512, 0, stream>>>(
      nullptr, PH, PL, W2sH, W2sL, b2, W3sH, W3sL, b3, out, N, HDIM);
}

// Round 10
// 383.862 us; speedup vs baseline: 4.2572x; 1.4085x over previous
//
#include <hip/hip_runtime.h>
#include <math.h>

#define HDIM 256

typedef float floatx4 __attribute__((ext_vector_type(4)));
typedef __bf16 bf16x8 __attribute__((ext_vector_type(8)));
typedef unsigned short ushortx4 __attribute__((ext_vector_type(4)));
typedef unsigned short ushortx8 __attribute__((ext_vector_type(8)));

#define AS1C(p) ((const __attribute__((address_space(1))) void*)(p))
#define AS3(p)  ((__attribute__((address_space(3))) void*)(p))

__device__ inline unsigned short bf16_rn(float f) {
  unsigned u = __float_as_uint(f);
  return (unsigned short)((u + 0x7FFFu + ((u >> 16) & 1u)) >> 16);
}

__device__ inline void split_f32(float f, unsigned short& h, unsigned short& l) {
  unsigned short hb = bf16_rn(f);
  float hf = __uint_as_float(((unsigned)hb) << 16);
  h = hb;
  l = bf16_rn(f - hf);
}

// ---------------- weight prep: all 5 weights in ONE launch ----------------
// Per weight: idx = ((cb*(K/32) + kt)*512 + kc*128 + col);
// chunk = W[kt*32+kc*8 + e][cb*128+col], e=0..7.

__device__ inline void prep_w_body(const float* __restrict__ W,
                                   unsigned short* __restrict__ SH,
                                   unsigned short* __restrict__ SL, int K, int idx) {
  int total = K * 32;
  int chunksPerCb = total >> 1;
  int cb = (idx >= chunksPerCb) ? 1 : 0;
  int rem = idx - cb * chunksPerCb;
  int kt = rem >> 9;
  int chunk = rem & 511;
  int kc = chunk >> 7;
  int col = chunk & 127;
  const float* src = W + (size_t)(kt * 32 + kc * 8) * HDIM + cb * 128 + col;
#pragma unroll
  for (int e = 0; e < 8; ++e) {
    unsigned short h, l;
    split_f32(src[(size_t)e * HDIM], h, l);
    SH[(size_t)idx * 8 + e] = h;
    SL[(size_t)idx * 8 + e] = l;
  }
}

__global__ __launch_bounds__(256)
void prep_w_all(const float* __restrict__ W1, unsigned short* __restrict__ S1H,
                unsigned short* __restrict__ S1L, int K1,
                const float* __restrict__ Wg1, unsigned short* __restrict__ G1H,
                unsigned short* __restrict__ G1L,
                const float* __restrict__ Wg2, unsigned short* __restrict__ G2H,
                unsigned short* __restrict__ G2L,
                const float* __restrict__ W2, unsigned short* __restrict__ S2H,
                unsigned short* __restrict__ S2L,
                const float* __restrict__ W3, unsigned short* __restrict__ S3H,
                unsigned short* __restrict__ S3L) {
  int gidx = blockIdx.x * 256 + threadIdx.x;
  int t1 = K1 * 32;
  int t256 = HDIM * 32;
  if (gidx < t1) {
    prep_w_body(W1, S1H, S1L, K1, gidx);
    return;
  }
  int r = gidx - t1;
  int which = r / t256;
  int idx = r - which * t256;
  if (which == 0)      prep_w_body(Wg1, G1H, G1L, HDIM, idx);
  else if (which == 1) prep_w_body(Wg2, G2H, G2L, HDIM, idx);
  else if (which == 2) prep_w_body(W2, S2H, S2L, HDIM, idx);
  else if (which == 3) prep_w_body(W3, S3H, S3L, HDIM, idx);
}

// ---------------- CSR build ----------------

__global__ __launch_bounds__(256)
void deg_count_kernel(const int* __restrict__ ei, int* __restrict__ deg, int E) {
  int e = blockIdx.x * 256 + threadIdx.x;
  if (e < E) atomicAdd(&deg[ei[E + e]], 1);
}

// block partial sums for the scan, plus dinv (deg^-1/2 with self-loop) fused in.
__global__ __launch_bounds__(256)
void block_sum_kernel(const int* __restrict__ deg, int* __restrict__ bsum,
                      float* __restrict__ dinv, int n) {
  __shared__ int sm[256];
  int t = threadIdx.x;
  int idx = blockIdx.x * 256 + t;
  int v = (idx < n) ? deg[idx] : 0;
  sm[t] = v;
  if (idx < n) dinv[idx] = 1.0f / sqrtf((float)v + 1.0f);
  __syncthreads();
  for (int off = 128; off > 0; off >>= 1) {
    if (t < off) sm[t] += sm[t + off];
    __syncthreads();
  }
  if (t == 0) bsum[blockIdx.x] = sm[0];
}

__global__ __launch_bounds__(256)
void scan_bsums_kernel(const int* __restrict__ bsum, int* __restrict__ boff,
                       int* __restrict__ rowptr, int nb, int n) {
  __shared__ int sm[256];
  int t = threadIdx.x;
  int v = (t < nb) ? bsum[t] : 0;
  sm[t] = v;
  __syncthreads();
  for (int off = 1; off < 256; off <<= 1) {
    int a = (t >= off) ? sm[t - off] : 0;
    __syncthreads();
    sm[t] += a;
    __syncthreads();
  }
  if (t < nb) boff[t] = sm[t] - v;
  if (t == 255) rowptr[n] = sm[255];
}

__global__ __launch_bounds__(256)
void scan_final_kernel(const int* __restrict__ deg, const int* __restrict__ boff,
                       int* __restrict__ rowptr, int* __restrict__ cursor, int n) {
  __shared__ int sm[256];
  int t = threadIdx.x;
  int idx = blockIdx.x * 256 + t;
  int v = (idx < n) ? deg[idx] : 0;
  sm[t] = v;
  __syncthreads();
  for (int off = 1; off < 256; off <<= 1) {
    int a = (t >= off) ? sm[t - off] : 0;
    __syncthreads();
    sm[t] += a;
    __syncthreads();
  }
  int excl = sm[t] - v + boff[blockIdx.x];
  if (idx < n) { rowptr[idx] = excl; cursor[idx] = excl; }
}

// fill CSR; also store wsrc[p] = dinv[src] so the aggregate pass reads weights
// contiguously instead of a dependent random dinv gather (one 64B line per edge).
__global__ __launch_bounds__(256)
void fill_csr_kernel(const int* __restrict__ ei, const float* __restrict__ dinv,
                     int* __restrict__ cursor, int* __restrict__ col,
                     float* __restrict__ wsrc, int E) {
  int e = blockIdx.x * 256 + threadIdx.x;
  if (e < E) {
    int s = ei[e];
    int d = ei[E + e];
    int p = atomicAdd(&cursor[d], 1);
    col[p] = s;
    wsrc[p] = dinv[s];
  }
}

// ---------------- GEMM 1: fp32 A, in-kernel split, tile 128x256, 512 threads ----------------
// Reads x fp32 directly, splits in regs, ds_writes hi/lo into the swizzled
// LDS layout the plane GEMM uses. Single-buffered: dbuf tested r1/r4/r7 —
// compiler drains vmcnt(0) at every barrier, so prefetch never survives it;
// doubling LDS only loses the 2-resident-block overlap that hides the drain.

template<bool BIAS, bool RELU>
__global__ __launch_bounds__(512, 4)
void mfma_gemm_sA(const float* __restrict__ A,
                  const unsigned short* __restrict__ SWH, const unsigned short* __restrict__ SWL,
                  const float* __restrict__ bias,
                  unsigned short* __restrict__ CH, unsigned short* __restrict__ CL,
                  int M, int K) {
  __shared__ __align__(16) unsigned short AsH[4096];
  __shared__ __align__(16) unsigned short AsL[4096];
  __shared__ __align__(16) unsigned short BsH[8192];
  __shared__ __align__(16) unsigned short BsL[8192];

  const int tid = threadIdx.x;
  const int w = tid >> 6;
  const int l = tid & 63;
  const int l15 = l & 15;
  const int quad = l >> 4;
  const int wm = w & 1;
  const int wn = w >> 1;
  const int bm = blockIdx.x * 128;
  const int ktc = K >> 5;
  const int chunksPerCb = ktc * 512;

  floatx4 acc[4][4];
#pragma unroll
  for (int i = 0; i < 4; ++i)
#pragma unroll
    for (int j = 0; j < 4; ++j) acc[i][j] = (floatx4){0.f, 0.f, 0.f, 0.f};

  // A chunk geometry (fixed per thread): chunk L=tid, row=L>>2, p=L&3, swizzled kc
  const int arow = tid >> 2;
  const int ap = tid & 3;
  const int akc = ap ^ (arow & 3) ^ ((arow >> 2) & 3);
  int agrow = bm + arow;
  if (agrow > M - 1) agrow = M - 1;
  const float* agp = A + (size_t)agrow * K + akc * 8;

  for (int kt = 0; kt < ktc; ++kt) {
    // fp32 A loads to regs (issued before the barrier; latency overlaps
    // previous iteration's MFMA + barrier wait)
    float4 f0 = *(const float4*)(agp + kt * 32);
    float4 f1 = *(const float4*)(agp + kt * 32 + 4);

    __syncthreads();

    // B staging via global_load_lds (issue first so its latency overlaps the split)
#pragma unroll
    for (int j = 0; j < 2; ++j) {
      int pos = j * 512 + w * 64 + l;
      int kc = pos >> 8;
      int within = pos & 255;
      int cb = within >> 7;
      int colL = within & 127;
      size_t gi = (size_t)cb * chunksPerCb + (size_t)kt * 512 + kc * 128 + colL;
      __builtin_amdgcn_global_load_lds(AS1C(SWH + gi * 8),
                                       AS3(&BsH[(j * 512 + w * 64) * 8]), 16, 0, 0);
      __builtin_amdgcn_global_load_lds(AS1C(SWL + gi * 8),
                                       AS3(&BsL[(j * 512 + w * 64) * 8]), 16, 0, 0);
    }

    // split + LDS write of A
    {
      float f[8] = {f0.x, f0.y, f0.z, f0.w, f1.x, f1.y, f1.z, f1.w};
      ushortx8 hh, ll;
#pragma unroll
      for (int e = 0; e < 8; ++e) {
        unsigned short h, lo;
        split_f32(f[e], h, lo);
        hh[e] = h;
        ll[e] = lo;
      }
      *(ushortx8*)&AsH[(size_t)tid * 8] = hh;
      *(ushortx8*)&AsL[(size_t)tid * 8] = ll;
    }

    __syncthreads();

    bf16x8 aH[4], aL[4];
#pragma unroll
    for (int fi = 0; fi < 4; ++fi) {
      int r = wm * 64 + fi * 16 + l15;
      int sw = quad ^ (r & 3) ^ ((r >> 2) & 3);
      aH[fi] = *(const bf16x8*)&AsH[(r * 4 + sw) * 8];
      aL[fi] = *(const bf16x8*)&AsL[(r * 4 + sw) * 8];
    }
#pragma unroll
    for (int fj = 0; fj < 4; ++fj) {
      int colG = wn * 64 + fj * 16 + l15;
      int cidx = quad * 256 + colG;
      bf16x8 bh = *(const bf16x8*)&BsH[cidx * 8];
      bf16x8 bl = *(const bf16x8*)&BsL[cidx * 8];
#pragma unroll
      for (int fi = 0; fi < 4; ++fi) {
        floatx4 t = acc[fi][fj];
        t = __builtin_amdgcn_mfma_f32_16x16x32_bf16(aH[fi], bl, t, 0, 0, 0);
        t = __builtin_amdgcn_mfma_f32_16x16x32_bf16(aL[fi], bh, t, 0, 0, 0);
        t = __builtin_amdgcn_mfma_f32_16x16x32_bf16(aH[fi], bh, t, 0, 0, 0);
        acc[fi][fj] = t;
      }
    }
  }

  float bcol[4];
#pragma unroll
  for (int fj = 0; fj < 4; ++fj)
    bcol[fj] = BIAS ? bias[wn * 64 + fj * 16 + l15] : 0.f;

#pragma unroll
  for (int fi = 0; fi < 4; ++fi) {
    int rb = bm + wm * 64 + fi * 16 + quad * 4;
#pragma unroll
    for (int r = 0; r < 4; ++r) {
      int row = rb + r;
      if (row < M) {
        size_t base = (size_t)row * HDIM + wn * 64 + l15;
#pragma unroll
        for (int fj = 0; fj < 4; ++fj) {
          float v = acc[fi][fj][r] + bcol[fj];
          if (RELU) v = fmaxf(v, 0.f);
          unsigned short h, lo;
          split_f32(v, h, lo);
          CH[base + fj * 16] = h;
          CL[base + fj * 16] = lo;
        }
      }
    }
  }
}

// ---------------- plane GEMM: tile 128x256, 512 threads, single-buffered ----------------
// NOTE on in-place use (CH==AH, CL==AL): each block stage-reads ONLY its own
// 128-row A panel and writes exactly that panel, strictly after its last
// stage-read (epilogue follows final barrier). No cross-block overlap, so
// in-place planes are safe at any occupancy. Every store depends on the full
// MFMA chain over the loads, so the formal restrict aliasing cannot reorder.

template<bool BIAS, bool RELU, bool SPLIT_OUT>
__global__ __launch_bounds__(512, 4)
void mfma_gemm_p(const unsigned short* __restrict__ AH, const unsigned short* __restrict__ AL,
                 const unsigned short* __restrict__ SWH, const unsigned short* __restrict__ SWL,
                 const float* __restrict__ bias,
                 float* __restrict__ C, unsigned short* __restrict__ CH,
                 unsigned short* __restrict__ CL, int M, int K) {
  __shared__ __align__(16) unsigned short AsH[4096];
  __shared__ __align__(16) unsigned short AsL[4096];
  __shared__ __align__(16) unsigned short BsH[8192];
  __shared__ __align__(16) unsigned short BsL[8192];

  const int tid = threadIdx.x;
  const int w = tid >> 6;
  const int l = tid & 63;
  const int l15 = l & 15;
  const int quad = l >> 4;
  const int wm = w & 1;
  const int wn = w >> 1;
  const int bm = blockIdx.x * 128;
  const int ktc = K >> 5;
  const int chunksPerCb = ktc * 512;

  floatx4 acc[4][4];
#pragma unroll
  for (int i = 0; i < 4; ++i)
#pragma unroll
    for (int j = 0; j < 4; ++j) acc[i][j] = (floatx4){0.f, 0.f, 0.f, 0.f};

  for (int kt = 0; kt < ktc; ++kt) {
    __syncthreads();

    {
      int L = tid;
      int row = L >> 2;
      int p = L & 3;
      int kc = p ^ (row & 3) ^ ((row >> 2) & 3);
      int grow = bm + row;
      if (grow > M - 1) grow = M - 1;
      const unsigned short* gH = AH + (size_t)grow * K + kt * 32 + kc * 8;
      const unsigned short* gL = AL + (size_t)grow * K + kt * 32 + kc * 8;
      __builtin_amdgcn_global_load_lds(AS1C(gH), AS3(&AsH[(w * 64) * 8]), 16, 0, 0);
      __builtin_amdgcn_global_load_lds(AS1C(gL), AS3(&AsL[(w * 64) * 8]), 16, 0, 0);
    }
#pragma unroll
    for (int j = 0; j < 2; ++j) {
      int pos = j * 512 + w * 64 + l;
      int kc = pos >> 8;
      int within = pos & 255;
      int cb = within >> 7;
      int colL = within & 127;
      size_t gi = (size_t)cb * chunksPerCb + (size_t)kt * 512 + kc * 128 + colL;
      __builtin_amdgcn_global_load_lds(AS1C(SWH + gi * 8),
                                       AS3(&BsH[(j * 512 + w * 64) * 8]), 16, 0, 0);
      __builtin_amdgcn_global_load_lds(AS1C(SWL + gi * 8),
                                       AS3(&BsL[(j * 512 + w * 64) * 8]), 16, 0, 0);
    }

    __syncthreads();

    bf16x8 aH[4], aL[4];
#pragma unroll
    for (int fi = 0; fi < 4; ++fi) {
      int r = wm * 64 + fi * 16 + l15;
      int sw = quad ^ (r & 3) ^ ((r >> 2) & 3);
      aH[fi] = *(const bf16x8*)&AsH[(r * 4 + sw) * 8];
      aL[fi] = *(const bf16x8*)&AsL[(r * 4 + sw) * 8];
    }
#pragma unroll
    for (int fj = 0; fj < 4; ++fj) {
      int colG = wn * 64 + fj * 16 + l15;
      int cidx = quad * 256 + colG;
      bf16x8 bh = *(const bf16x8*)&BsH[cidx * 8];
      bf16x8 bl = *(const bf16x8*)&BsL[cidx * 8];
#pragma unroll
      for (int fi = 0; fi < 4; ++fi) {
        floatx4 t = acc[fi][fj];
        t = __builtin_amdgcn_mfma_f32_16x16x32_bf16(aH[fi], bl, t, 0, 0, 0);
        t = __builtin_amdgcn_mfma_f32_16x16x32_bf16(aL[fi], bh, t, 0, 0, 0);
        t = __builtin_amdgcn_mfma_f32_16x16x32_bf16(aH[fi], bh, t, 0, 0, 0);
        acc[fi][fj] = t;
      }
    }
  }

  float bcol[4];
#pragma unroll
  for (int fj = 0; fj < 4; ++fj)
    bcol[fj] = BIAS ? bias[wn * 64 + fj * 16 + l15] : 0.f;

#pragma unroll
  for (int fi = 0; fi < 4; ++fi) {
    int rb = bm + wm * 64 + fi * 16 + quad * 4;
#pragma unroll
    for (int r = 0; r < 4; ++r) {
      int row = rb + r;
      if (row < M) {
        size_t base = (size_t)row * HDIM + wn * 64 + l15;
        if (SPLIT_OUT) {
#pragma unroll
          for (int fj = 0; fj < 4; ++fj) {
            float v = acc[fi][fj][r] + bcol[fj];
            if (RELU) v = fmaxf(v, 0.f);
            unsigned short h, lo;
            split_f32(v, h, lo);
            CH[base + fj * 16] = h;
            CL[base + fj * 16] = lo;
          }
        } else {
#pragma unroll
          for (int fj = 0; fj < 4; ++fj) {
            float v = acc[fi][fj][r] + bcol[fj];
            if (RELU) v = fmaxf(v, 0.f);
            C[base + fj * 16] = v;
          }
        }
      }
    }
  }
}

// ---------------- fused GEMM + softmax: tile 128x256, 512 threads ----------------
// Reads A-planes from workspace (PH/PL), writes fp32 to d_out: disjoint regions,
// no in-place hazard at any occupancy.

__global__ __launch_bounds__(512, 4)
void mfma_gemm_softmax(const unsigned short* __restrict__ AH, const unsigned short* __restrict__ AL,
                       const unsigned short* __restrict__ SWH, const unsigned short* __restrict__ SWL,
                       const float* __restrict__ bias, float* __restrict__ out, int M, int K) {
  __shared__ __align__(16) unsigned short AsH[4096];
  __shared__ __align__(16) unsigned short AsL[4096];
  __shared__ __align__(16) unsigned short BsH[8192];
  __shared__ __align__(16) unsigned short BsL[8192];
  __shared__ float smax[128 * 4];
  __shared__ float ssum[128 * 4];

  const int tid = threadIdx.x;
  const int w = tid >> 6;
  const int l = tid & 63;
  const int l15 = l & 15;
  const int quad = l >> 4;
  const int wm = w & 1;
  const int wn = w >> 1;
  const int bm = blockIdx.x * 128;
  const int ktc = K >> 5;
  const int chunksPerCb = ktc * 512;

  floatx4 acc[4][4];
#pragma unroll
  for (int i = 0; i < 4; ++i)
#pragma unroll
    for (int j = 0; j < 4; ++j) acc[i][j] = (floatx4){0.f, 0.f, 0.f, 0.f};

  for (int kt = 0; kt < ktc; ++kt) {
    __syncthreads();

    {
      int L = tid;
      int row = L >> 2;
      int p = L & 3;
      int kc = p ^ (row & 3) ^ ((row >> 2) & 3);
      int grow = bm + row;
      if (grow > M - 1) grow = M - 1;
      const unsigned short* gH = AH + (size_t)grow * K + kt * 32 + kc * 8;
      const unsigned short* gL = AL + (size_t)grow * K + kt * 32 + kc * 8;
      __builtin_amdgcn_global_load_lds(AS1C(gH), AS3(&AsH[(w * 64) * 8]), 16, 0, 0);
      __builtin_amdgcn_global_load_lds(AS1C(gL), AS3(&AsL[(w * 64) * 8]), 16, 0, 0);
    }
#pragma unroll
    for (int j = 0; j < 2; ++j) {
      int pos = j * 512 + w * 64 + l;
      int kc = pos >> 8;
      int within = pos & 255;
      int cb = within >> 7;
      int colL = within & 127;
      size_t gi = (size_t)cb * chunksPerCb + (size_t)kt * 512 + kc * 128 + colL;
      __builtin_amdgcn_global_load_lds(AS1C(SWH + gi * 8),
                                       AS3(&BsH[(j * 512 + w * 64) * 8]), 16, 0, 0);
      __builtin_amdgcn_global_load_lds(AS1C(SWL + gi * 8),
                                       AS3(&BsL[(j * 512 + w * 64) * 8]), 16, 0, 0);
    }

    __syncthreads();

    bf16x8 aH[4], aL[4];
#pragma unroll
    for (int fi = 0; fi < 4; ++fi) {
      int r = wm * 64 + fi * 16 + l15;
      int sw = quad ^ (r & 3) ^ ((r >> 2) & 3);
      aH[fi] = *(const bf16x8*)&AsH[(r * 4 + sw) * 8];
      aL[fi] = *(const bf16x8*)&AsL[(r * 4 + sw) * 8];
    }
#pragma unroll
    for (int fj = 0; fj < 4; ++fj) {
      int colG = wn * 64 + fj * 16 + l15;
      int cidx = quad * 256 + colG;
      bf16x8 bh = *(const bf16x8*)&BsH[cidx * 8];
      bf16x8 bl = *(const bf16x8*)&BsL[cidx * 8];
#pragma unroll
      for (int fi = 0; fi < 4; ++fi) {
        floatx4 t = acc[fi][fj];
        t = __builtin_amdgcn_mfma_f32_16x16x32_bf16(aH[fi], bl, t, 0, 0, 0);
        t = __builtin_amdgcn_mfma_f32_16x16x32_bf16(aL[fi], bh, t, 0, 0, 0);
        t = __builtin_amdgcn_mfma_f32_16x16x32_bf16(aH[fi], bh, t, 0, 0, 0);
        acc[fi][fj] = t;
      }
    }
  }

  float bcol[4];
#pragma unroll
  for (int fj = 0; fj < 4; ++fj)
    bcol[fj] = bias[wn * 64 + fj * 16 + l15];

#pragma unroll
  for (int fi = 0; fi < 4; ++fi) {
#pragma unroll
    for (int r = 0; r < 4; ++r) {
      float mv = -3.4e38f;
#pragma unroll
      for (int fj = 0; fj < 4; ++fj) mv = fmaxf(mv, acc[fi][fj][r] + bcol[fj]);
#pragma unroll
      for (int off = 1; off < 16; off <<= 1) mv = fmaxf(mv, __shfl_xor(mv, off));
      int row = wm * 64 + fi * 16 + quad * 4 + r;
      if (l15 == 0) smax[row * 4 + wn] = mv;
    }
  }
  __syncthreads();

#pragma unroll
  for (int fi = 0; fi < 4; ++fi) {
#pragma unroll
    for (int r = 0; r < 4; ++r) {
      int row = wm * 64 + fi * 16 + quad * 4 + r;
      float gm = fmaxf(fmaxf(smax[row * 4 + 0], smax[row * 4 + 1]),
                       fmaxf(smax[row * 4 + 2], smax[row * 4 + 3]));
      float s = 0.f;
#pragma unroll
      for (int fj = 0; fj < 4; ++fj) {
        float p = expf(acc[fi][fj][r] + bcol[fj] - gm);
        acc[fi][fj][r] = p;
        s += p;
      }
#pragma unroll
      for (int off = 1; off < 16; off <<= 1) s += __shfl_xor(s, off);
      if (l15 == 0) ssum[row * 4 + wn] = s;
    }
  }
  __syncthreads();

#pragma unroll
  for (int fi = 0; fi < 4; ++fi) {
#pragma unroll
    for (int r = 0; r < 4; ++r) {
      int row = wm * 64 + fi * 16 + quad * 4 + r;
      int grow = bm + row;
      if (grow < M) {
        float inv = 1.0f / (ssum[row * 4 + 0] + ssum[row * 4 + 1] +
                            ssum[row * 4 + 2] + ssum[row * 4 + 3]);
        float* Cp = out + (size_t)grow * HDIM + wn * 64 + l15;
#pragma unroll
        for (int fj = 0; fj < 4; ++fj) Cp[fj * 16] = acc[fi][fj][r] * inv;
      }
    }
  }
}

// ---------------- GCN aggregation: two-phase batched gather, one row per wave ----------------
// 256-thr / 4-row blocks, CP-scheduled: measured optimum (54.1-54.5us) vs
// persistent static waves (59.7), 1024-thr blocks (57.7), atomic work queue
// (667 — cross-XCD atomic serialization), half-split dispatches (+30us gaps).
// At 54.5us this moves 223MB at ~4.1TB/s effective on a random-gather mix:
// structural roofline for this access pattern.

__global__ __launch_bounds__(256)
void aggregate_b(const float* __restrict__ t, const float* __restrict__ dinv,
                 const int* __restrict__ rowptr, const int* __restrict__ col,
                 const float* __restrict__ wsrc, const float* __restrict__ bias,
                 unsigned short* __restrict__ OH, unsigned short* __restrict__ OL, int n) {
  int gw = (int)((blockIdx.x * 256 + threadIdx.x) >> 6);
  int lane = threadIdx.x & 63;
  if (gw >= n) return;
  float di = dinv[gw];
  float4 v = ((const float4*)(t + (size_t)gw * HDIM))[lane];
  float ss = di * di;
  float a0 = v.x * ss, a1 = v.y * ss, a2 = v.z * ss, a3 = v.w * ss;
  int e0 = rowptr[gw], e1 = rowptr[gw + 1];

  for (int base = e0; base < e1; base += 8) {
    int cs[8];
    float wv[8];
#pragma unroll
    for (int i = 0; i < 8; ++i) {
      int e = base + i;
      if (e > e1 - 1) e = e1 - 1;
      cs[i] = col[e];
      wv[i] = wsrc[e];
    }
    float wg[8];
#pragma unroll
    for (int i = 0; i < 8; ++i)
      wg[i] = (base + i < e1) ? wv[i] * di : 0.f;
    float4 rw[8];
#pragma unroll
    for (int i = 0; i < 8; ++i)
      rw[i] = ((const float4*)(t + (size_t)cs[i] * HDIM))[lane];
#pragma unroll
    for (int i = 0; i < 8; ++i) {
      a0 = fmaf(rw[i].x, wg[i], a0);
      a1 = fmaf(rw[i].y, wg[i], a1);
      a2 = fmaf(rw[i].z, wg[i], a2);
      a3 = fmaf(rw[i].w, wg[i], a3);
    }
  }

  float4 bb = ((const float4*)bias)[lane];
  float r0 = fmaxf(a0 + bb.x, 0.f);
  float r1 = fmaxf(a1 + bb.y, 0.f);
  float r2 = fmaxf(a2 + bb.z, 0.f);
  float r3 = fmaxf(a3 + bb.w, 0.f);
  unsigned short h0, h1, h2, h3, l0, l1, l2, l3;
  split_f32(r0, h0, l0);
  split_f32(r1, h1, l1);
  split_f32(r2, h2, l2);
  split_f32(r3, h3, l3);
  ((ushortx4*)(OH + (size_t)gw * HDIM))[lane] = (ushortx4){h0, h1, h2, h3};
  ((ushortx4*)(OL + (size_t)gw * HDIM))[lane] = (ushortx4){l0, l1, l2, l3};
}

// ---------------- launch ----------------

extern "C" void kernel_launch(void* const* d_in, const int* in_sizes, int n_in,
                              void* d_out, int out_size, void* d_ws, size_t ws_size,
                              hipStream_t stream) {
  const float* x   = (const float*)d_in[0];
  const int*   ei  = (const int*)d_in[1];
  const float* W1  = (const float*)d_in[2];
  const float* b1  = (const float*)d_in[3];
  const float* Wg1 = (const float*)d_in[4];
  const float* bg1 = (const float*)d_in[5];
  const float* Wg2 = (const float*)d_in[6];
  const float* bg2 = (const float*)d_in[7];
  const float* W2  = (const float*)d_in[8];
  const float* b2  = (const float*)d_in[9];
  const float* W3  = (const float*)d_in[10];
  const float* b3  = (const float*)d_in[11];
  float* out = (float*)d_out;

  const int K1 = in_sizes[2] / HDIM;  // 128
  const int N  = in_sizes[0] / K1;    // 50000
  const int E  = in_sizes[1] / 2;     // 300000

  char* w = (char*)d_ws;
  auto alloc = [&](size_t bytes) -> char* {
    char* p = w;
    w += (bytes + 255) & ~(size_t)255;
    return p;
  };
  unsigned short* PH = (unsigned short*)alloc((size_t)N * HDIM * 2);
  unsigned short* PL = (unsigned short*)alloc((size_t)N * HDIM * 2);
  float* dinv   = (float*)alloc((size_t)N * sizeof(float));
  int*   deg    = (int*)alloc((size_t)N * sizeof(int));
  int*   rowptr = (int*)alloc((size_t)(N + 1) * sizeof(int));
  int*   cursor = (int*)alloc((size_t)N * sizeof(int));
  int*   col    = (int*)alloc((size_t)E * sizeof(int));
  float* wcsr   = (float*)alloc((size_t)E * sizeof(float));
  const int nb  = (N + 255) / 256;
  int*   bsum   = (int*)alloc((size_t)nb * sizeof(int));
  int*   boff   = (int*)alloc((size_t)nb * sizeof(int));
  unsigned short* W1sH  = (unsigned short*)alloc((size_t)HDIM * K1 * 2);
  unsigned short* W1sL  = (unsigned short*)alloc((size_t)HDIM * K1 * 2);
  unsigned short* Wg1sH = (unsigned short*)alloc((size_t)HDIM * HDIM * 2);
  unsigned short* Wg1sL = (unsigned short*)alloc((size_t)HDIM * HDIM * 2);
  unsigned short* Wg2sH = (unsigned short*)alloc((size_t)HDIM * HDIM * 2);
  unsigned short* Wg2sL = (unsigned short*)alloc((size_t)HDIM * HDIM * 2);
  unsigned short* W2sH  = (unsigned short*)alloc((size_t)HDIM * HDIM * 2);
  unsigned short* W2sL  = (unsigned short*)alloc((size_t)HDIM * HDIM * 2);
  unsigned short* W3sH  = (unsigned short*)alloc((size_t)HDIM * HDIM * 2);
  unsigned short* W3sL  = (unsigned short*)alloc((size_t)HDIM * HDIM * 2);

  const int ge = (E + 255) / 256;

  const int prepChunks = K1 * 32 + 4 * HDIM * 32;
  prep_w_all<<<(prepChunks + 255) / 256, 256, 0, stream>>>(
      W1, W1sH, W1sL, K1, Wg1, Wg1sH, Wg1sL, Wg2, Wg2sH, Wg2sL,
      W2, W2sH, W2sL, W3, W3sH, W3sL);

  hipMemsetAsync(deg, 0, (size_t)N * sizeof(int), stream);
  deg_count_kernel<<<ge, 256, 0, stream>>>(ei, deg, E);
  block_sum_kernel<<<nb, 256, 0, stream>>>(deg, bsum, dinv, N);
  scan_bsums_kernel<<<1, 256, 0, stream>>>(bsum, boff, rowptr, nb, N);
  scan_final_kernel<<<nb, 256, 0, stream>>>(deg, boff, rowptr, cursor, N);
  fill_csr_kernel<<<ge, 256, 0, stream>>>(ei, dinv, cursor, col, wcsr, E);

  const int g128 = (N + 127) / 128;
  const int gagg = (N + 3) / 4;

  // h0 = relu(x@W1+b1) -> planes P (fp32 A split fused in-kernel)
  mfma_gemm_sA<true, true><<<g128, 512, 0, stream>>>(x, W1sH, W1sL, b1, PH, PL, N, K1);
  // t1 = h0@Wg1 -> out (fp32 scratch in d_out)
  mfma_gemm_p<false, false, false><<<g128, 512, 0, stream>>>(PH, PL, Wg1sH, Wg1sL, nullptr, out, nullptr, nullptr, N, HDIM);
  // h1 = relu(agg(t1)+bg1) -> planes P
  aggregate_b<<<gagg, 256, 0, stream>>>(out, dinv, rowptr, col, wcsr, bg1, PH, PL, N);
  // t2 = h1@Wg2 -> out
  mfma_gemm_p<false, false, false><<<g128, 512, 0, stream>>>(PH, PL, Wg2sH, Wg2sL, nullptr, out, nullptr, nullptr, N, HDIM);
  // h2 = relu(agg(t2)+bg2) -> planes P
  aggregate_b<<<gagg, 256, 0, stream>>>(out, dinv, rowptr, col, wcsr, bg2, PH, PL, N);
  // h3 = relu(h2@W2+b2) -> planes P IN-PLACE (safe: per-block panel ownership)
  mfma_gemm_p<true, true, true><<<g128, 512, 0, stream>>>(PH, PL, W2sH, W2sL, b2, nullptr, PH, PL, N, HDIM);
  // out = softmax(h3@W3+b3): reads ws planes, writes d_out (disjoint)
  mfma_gemm_softmax<<<g128, 512, 0, stream>>>(PH, PL, W3sH, W3sL, b3, out, N, HDIM);
}